// Round 18
// baseline (235.681 us; speedup 1.0000x reference)
//
#include <hip/hip_runtime.h>
#include <hip/hip_bf16.h>

#define AS1 __attribute__((address_space(1)))
#define AS3 __attribute__((address_space(3)))

typedef __bf16 bf16;
typedef __attribute__((ext_vector_type(8))) __bf16 bf16x8;
typedef __attribute__((ext_vector_type(4))) __bf16 bf16x4;
typedef __attribute__((ext_vector_type(4))) float f32x4;

#define NB 2
#define NS 2048
#define ND 1024
#define NH 16
#define NF 4096
#define NHD 64
#define NM (NB*NS)   // 4096 tokens

__device__ __forceinline__ void gload16(const void* g, void* l) {
  __builtin_amdgcn_global_load_lds((AS1 void*)g, (AS3 void*)l, 16, 0, 0);
}

// ---------------- fused prologue: 6 weight transposes (fp32->bf16) + LN1
// bid < 3072: weight transpose tiles.  bid >= 3072: LN1 row (bid-3072).
__global__ void tb_pre(const float* __restrict__ x, const float* __restrict__ g1,
                       const float* __restrict__ be1, bf16* __restrict__ Abuf,
                       const float* __restrict__ Wq, const float* __restrict__ Wk,
                       const float* __restrict__ Wv, const float* __restrict__ Wp,
                       const float* __restrict__ W1, const float* __restrict__ W2,
                       bf16* __restrict__ WqT, bf16* __restrict__ WkT,
                       bf16* __restrict__ WvT, bf16* __restrict__ WpT,
                       bf16* __restrict__ W1T, bf16* __restrict__ W2T) {
  __shared__ float t[64][65];
  __shared__ float red[8];
  const int bid = blockIdx.x;
  const int tid = threadIdx.x;
  if (bid >= 3072) {
    // ---- LN1 on row (bid-3072) ----
    const int row = bid - 3072;
    const float4 v = ((const float4*)(x + (size_t)row * ND))[tid];
    float s  = v.x + v.y + v.z + v.w;
    float ss = v.x*v.x + v.y*v.y + v.z*v.z + v.w*v.w;
#pragma unroll
    for (int off = 32; off; off >>= 1) {
      s  += __shfl_xor(s,  off, 64);
      ss += __shfl_xor(ss, off, 64);
    }
    const int lane = tid & 63, wv = tid >> 6;
    if (lane == 0) { red[wv] = s; red[4 + wv] = ss; }
    __syncthreads();
    s  = red[0] + red[1] + red[2] + red[3];
    ss = red[4] + red[5] + red[6] + red[7];
    const float mu = s * (1.0f / ND);
    const float var = ss * (1.0f / ND) - mu * mu;
    const float rstd = rsqrtf(var + 1e-5f);
    const float4 gv = ((const float4*)g1)[tid];
    const float4 bv = ((const float4*)be1)[tid];
    bf16x4 o;
    o[0] = (bf16)((v.x - mu) * rstd * gv.x + bv.x);
    o[1] = (bf16)((v.y - mu) * rstd * gv.y + bv.y);
    o[2] = (bf16)((v.z - mu) * rstd * gv.z + bv.z);
    o[3] = (bf16)((v.w - mu) * rstd * gv.w + bv.w);
    ((bf16x4*)(Abuf + (size_t)row * ND))[tid] = o;
    return;
  }
  // ---- weight transpose tile ----
  const float* W; bf16* Wt; int K, N, nb, kb;
  if (bid < 1024) {
    const int z = bid >> 8, i = bid & 255;
    K = ND; N = ND; nb = (i & 15) << 6; kb = (i >> 4) << 6;
    W  = (z == 0) ? Wq  : (z == 1) ? Wk  : (z == 2) ? Wv  : Wp;
    Wt = (z == 0) ? WqT : (z == 1) ? WkT : (z == 2) ? WvT : WpT;
  } else if (bid < 2048) {
    const int i = bid - 1024;
    K = ND; N = NF; nb = (i & 63) << 6; kb = (i >> 6) << 6;
    W = W1; Wt = W1T;
  } else {
    const int i = bid - 2048;
    K = NF; N = ND; nb = (i & 15) << 6; kb = (i >> 4) << 6;
    W = W2; Wt = W2T;
  }
#pragma unroll
  for (int i = 0; i < 16; ++i) {
    const int lin = tid + (i << 8);
    const int r = lin >> 6, c = lin & 63;
    t[r][c] = W[(size_t)(kb + r) * N + nb + c];
  }
  __syncthreads();
#pragma unroll
  for (int i = 0; i < 16; ++i) {
    const int lin = tid + (i << 8);
    const int r = lin >> 6, c = lin & 63;  // r: n-local, c: k-local
    Wt[(size_t)(nb + r) * K + kb + c] = (bf16)t[c][r];
  }
}

// ---------------- layernorm (LN2): fp32 row -> bf16 row (one block per row)
__global__ void tb_lnorm(const float* __restrict__ xin, const float* __restrict__ g,
                         const float* __restrict__ be, bf16* __restrict__ outp) {
  const int row = blockIdx.x;
  const int tid = threadIdx.x;
  const float4 v = ((const float4*)(xin + (size_t)row * ND))[tid];
  float s  = v.x + v.y + v.z + v.w;
  float ss = v.x*v.x + v.y*v.y + v.z*v.z + v.w*v.w;
#pragma unroll
  for (int off = 32; off; off >>= 1) {
    s  += __shfl_xor(s,  off, 64);
    ss += __shfl_xor(ss, off, 64);
  }
  __shared__ float red[8];
  const int lane = tid & 63, wv = tid >> 6;
  if (lane == 0) { red[wv] = s; red[4 + wv] = ss; }
  __syncthreads();
  s  = red[0] + red[1] + red[2] + red[3];
  ss = red[4] + red[5] + red[6] + red[7];
  const float mu = s * (1.0f / ND);
  const float var = ss * (1.0f / ND) - mu * mu;
  const float rstd = rsqrtf(var + 1e-5f);
  const float4 gv = ((const float4*)g)[tid];
  const float4 bv = ((const float4*)be)[tid];
  bf16x4 o;
  o[0] = (bf16)((v.x - mu) * rstd * gv.x + bv.x);
  o[1] = (bf16)((v.y - mu) * rstd * gv.y + bv.y);
  o[2] = (bf16)((v.z - mu) * rstd * gv.z + bv.z);
  o[3] = (bf16)((v.w - mu) * rstd * gv.w + bv.w);
  ((bf16x4*)(outp + (size_t)row * ND))[tid] = o;
}

// ---------------- GEMM 128x128: C = A * Bt^T (+bias epilogue)
// MODE 0: z==0 (Q, pre-scaled 0.125*log2e -> scores natively base-2) /
//         z==1 (K): bf16 scatter to [B,H,S,HD];
//         z==2 (V): write V^T directly to vt[bh][hd][s] via LDS transpose.
// MODE 2: out bf16 = gelu(acc + bias)     (stride NF)
template <int MODE>
__global__ void __launch_bounds__(256, 2)
tb_gemm(const bf16* __restrict__ A,
        const bf16* __restrict__ B0, const bf16* __restrict__ B1, const bf16* __restrict__ B2,
        const float* __restrict__ bias0, const float* __restrict__ bias1, const float* __restrict__ bias2,
        void* __restrict__ o0, void* __restrict__ o1, void* __restrict__ o2,
        int Ktot) {
  __shared__ __align__(16) bf16 SM[2][128 * 64];   // As = SM[0], Bs = SM[1]
  bf16* const As = SM[0];
  bf16* const Bs = SM[1];
  const bf16* Bt = B0; const float* bias = bias0; void* outp = o0;
  if (MODE == 0) {
    if (blockIdx.z == 1)      { Bt = B1; bias = bias1; outp = o1; }
    else if (blockIdx.z == 2) { Bt = B2; bias = bias2; outp = o2; }
  }
  const int tid = threadIdx.x;
  const int lane = tid & 63, wv = tid >> 6;
  const int wr = wv >> 1, wc = wv & 1;
  const int m0 = blockIdx.y * 128, n0 = blockIdx.x * 128;

  f32x4 acc[4][4] = {};

  const int srow = (wv << 3) + (lane >> 3);
  const int scb  = ((lane & 7) << 4);

  for (int k0 = 0; k0 < Ktot; k0 += 64) {
    __syncthreads();
#pragma unroll
    for (int i = 0; i < 4; ++i) {
      const int row = i * 32 + srow;
      const int cb = scb ^ ((row & 7) << 4);
      gload16(A  + (size_t)(m0 + row) * Ktot + k0 + (cb >> 1), (char*)As + i * 4096 + wv * 1024);
      gload16(Bt + (size_t)(n0 + row) * Ktot + k0 + (cb >> 1), (char*)Bs + i * 4096 + wv * 1024);
    }
    __syncthreads();
#pragma unroll
    for (int kk = 0; kk < 2; ++kk) {
      bf16x8 af[4], bfr[4];
#pragma unroll
      for (int mi = 0; mi < 4; ++mi) {
        const int row = wr * 64 + mi * 16 + (lane & 15);
        const int cb = (kk * 64 + ((lane >> 4) << 4)) ^ ((row & 7) << 4);
        af[mi] = *(const bf16x8*)((const char*)As + row * 128 + cb);
      }
#pragma unroll
      for (int ni = 0; ni < 4; ++ni) {
        const int row = wc * 64 + ni * 16 + (lane & 15);
        const int cb = (kk * 64 + ((lane >> 4) << 4)) ^ ((row & 7) << 4);
        bfr[ni] = *(const bf16x8*)((const char*)Bs + row * 128 + cb);
      }
#pragma unroll
      for (int mi = 0; mi < 4; ++mi)
#pragma unroll
        for (int ni = 0; ni < 4; ++ni)
          acc[mi][ni] = __builtin_amdgcn_mfma_f32_16x16x32_bf16(af[mi], bfr[ni], acc[mi][ni], 0, 0, 0);
    }
  }

  if (MODE == 0 && blockIdx.z == 2) {
    // ---- V: transpose via LDS, write vt[bh][hd][s] coalesced ----
    __syncthreads();                       // staging reads done; reuse SM
    bf16* const T = (bf16*)SM;             // [128 col][128 row], row^((col&7)<<3)
#pragma unroll
    for (int mi = 0; mi < 4; ++mi)
#pragma unroll
      for (int ni = 0; ni < 4; ++ni) {
        const int lcol = wc * 64 + ni * 16 + (lane & 15);
        const int lr0  = wr * 64 + mi * 16 + ((lane >> 4) << 2);
        bf16x4 tv;
#pragma unroll
        for (int r = 0; r < 4; ++r)
          tv[r] = (bf16)(acc[mi][ni][r] + bias[n0 + lcol]);
        *(bf16x4*)&T[lcol * 128 + (lr0 ^ ((lcol & 7) << 3))] = tv;
      }
    __syncthreads();
    const int col = tid & 127, rh = tid >> 7;
    const int gc = n0 + col, h = gc >> 6, hd = gc & 63;
    const int b = m0 >> 11, s0 = m0 & 2047;
    bf16* dst = (bf16*)outp + (((size_t)(b * NH + h)) * NHD + hd) * NS + s0 + rh * 64;
#pragma unroll
    for (int bb = 0; bb < 8; ++bb) {
      const int blk = rh * 8 + bb;
      *(bf16x8*)(dst + bb * 8) =
          *(const bf16x8*)&T[col * 128 + ((blk << 3) ^ ((col & 7) << 3))];
    }
    return;
  }

  // Q pre-scale folds 1/sqrt(HD) AND log2(e): scores become base-2 exponents.
  const float scale = (MODE == 0 && blockIdx.z == 0) ? 0.18033688f : 1.0f;
#pragma unroll
  for (int mi = 0; mi < 4; ++mi) {
#pragma unroll
    for (int ni = 0; ni < 4; ++ni) {
      const int rbase = m0 + wr * 64 + mi * 16 + ((lane >> 4) << 2);
      const int gcol  = n0 + wc * 64 + ni * 16 + (lane & 15);
#pragma unroll
      for (int r = 0; r < 4; ++r) {
        const int grow = rbase + r;
        const float val = (acc[mi][ni][r] + bias[gcol]) * scale;
        if (MODE == 0) {
          const int b = grow >> 11, sIdx = grow & 2047;
          const int h = gcol >> 6, hd = gcol & 63;
          ((bf16*)outp)[(((size_t)(b * NH + h)) * NS + sIdx) * NHD + hd] = (bf16)val;
        } else {
          const float gelu = 0.5f * val * (1.0f + erff(val * 0.70710678f));
          ((bf16*)outp)[(size_t)grow * NF + gcol] = (bf16)gelu;
        }
      }
    }
  }
}

// ---------------- GEMM 64x64 + residual (proj & FFN2): occupancy-first tile
// Grid 1024 blocks (64 m x 16 n), 32KB LDS -> 4 blocks/CU.
// XCD m-grouped: each XCD owns 8 m-panels (4MB A, L2-resident); B L3-served.
__global__ void __launch_bounds__(256, 4)
tb_gemm64(const bf16* __restrict__ A, const bf16* __restrict__ Bt,
          const float* __restrict__ bias, const float* __restrict__ resid,
          float* __restrict__ outp, int Ktot) {
  __shared__ __align__(16) bf16 As[2][64 * 64];
  __shared__ __align__(16) bf16 Bs[2][64 * 64];
  const int bid = blockIdx.x;            // 0..1023
  const int xcd = bid & 7, j = bid >> 3; // j: 0..127
  const int m0 = (xcd * 8 + (j & 7)) * 64;   // 64 m-tiles, 8 per XCD
  const int n0 = (j >> 3) * 64;              // 16 n-tiles
  const int tid = threadIdx.x;
  const int lane = tid & 63, wv = tid >> 6;
  const int wr = wv >> 1, wc = wv & 1;       // wave tile: 32 x 32

  f32x4 acc[2][2] = {};

  const int srow = (wv << 3) + (lane >> 3);
  const int scb  = ((lane & 7) << 4);
  const int NT = Ktot >> 6;

#define GSTAGE64(buf, t_) do {                                                 \
    _Pragma("unroll")                                                          \
    for (int i_ = 0; i_ < 2; ++i_) {                                           \
      const int row_ = i_ * 32 + srow;                                         \
      const int cb_ = scb ^ ((row_ & 7) << 4);                                 \
      gload16(A  + (size_t)(m0 + row_) * Ktot + ((t_) << 6) + (cb_ >> 1),      \
              (char*)As[buf] + i_ * 4096 + wv * 1024);                         \
      gload16(Bt + (size_t)(n0 + row_) * Ktot + ((t_) << 6) + (cb_ >> 1),      \
              (char*)Bs[buf] + i_ * 4096 + wv * 1024);                         \
    } } while (0)

  GSTAGE64(0, 0);
  asm volatile("s_waitcnt vmcnt(0)" ::: "memory");
  __builtin_amdgcn_s_barrier();

  for (int t = 0; t < NT; ++t) {
    const int cur = t & 1;
    if (t + 1 < NT) GSTAGE64(cur ^ 1, t + 1);   // prefetch flies under MFMA
    const char* Ab = (const char*)As[cur];
    const char* Bb = (const char*)Bs[cur];
#pragma unroll
    for (int kk = 0; kk < 2; ++kk) {
      bf16x8 af[2], bfr[2];
#pragma unroll
      for (int mi = 0; mi < 2; ++mi) {
        const int row = wr * 32 + mi * 16 + (lane & 15);
        const int cb = (kk * 64 + ((lane >> 4) << 4)) ^ ((row & 7) << 4);
        af[mi] = *(const bf16x8*)(Ab + row * 128 + cb);
      }
#pragma unroll
      for (int ni = 0; ni < 2; ++ni) {
        const int row = wc * 32 + ni * 16 + (lane & 15);
        const int cb = (kk * 64 + ((lane >> 4) << 4)) ^ ((row & 7) << 4);
        bfr[ni] = *(const bf16x8*)(Bb + row * 128 + cb);
      }
#pragma unroll
      for (int mi = 0; mi < 2; ++mi)
#pragma unroll
        for (int ni = 0; ni < 2; ++ni)
          acc[mi][ni] = __builtin_amdgcn_mfma_f32_16x16x32_bf16(af[mi], bfr[ni], acc[mi][ni], 0, 0, 0);
    }
    if (t + 1 < NT) {
      asm volatile("s_waitcnt vmcnt(0)" ::: "memory");
      __builtin_amdgcn_s_barrier();
    }
  }
#undef GSTAGE64

  // epilogue: out = resid + acc + bias (fp32, stride ND)
#pragma unroll
  for (int mi = 0; mi < 2; ++mi) {
#pragma unroll
    for (int ni = 0; ni < 2; ++ni) {
      const int rbase = m0 + wr * 32 + mi * 16 + ((lane >> 4) << 2);
      const int gcol  = n0 + wc * 32 + ni * 16 + (lane & 15);
#pragma unroll
      for (int r = 0; r < 4; ++r) {
        const size_t idx = (size_t)(rbase + r) * ND + gcol;
        outp[idx] = resid[idx] + acc[mi][ni][r] + bias[gcol];
      }
    }
  }
}

// ---------------- causal flash attention (round-11 proven; base-2 scores; T5)
__global__ void __launch_bounds__(256, 4)
tb_attn(const bf16* __restrict__ qg, const bf16* __restrict__ kg,
        const bf16* __restrict__ vtg, bf16* __restrict__ og) {
  __shared__ __align__(16) bf16 Ks[2][64 * 64];
  __shared__ __align__(16) bf16 Vts[2][64 * 64];
  __shared__ __align__(16) bf16 Ps[4][16 * 64];
  const int bid = blockIdx.x;
  const int u = bid & 255, v = bid >> 8;
  const int bh = u & 31;
  const int s = ((u >> 5) << 2) + v;                    // 0..31
  const int qt = (s & 1) ? (31 - (s >> 1)) : (s >> 1);  // balanced per-CU mix
  const int tid = threadIdx.x;
  const int lane = tid & 63, wv = tid >> 6;
  const bf16* Qp  = qg  + (size_t)bh * NS * NHD;
  const bf16* Kp  = kg  + (size_t)bh * NS * NHD;
  const bf16* Vtp = vtg + (size_t)bh * NHD * NS;   // [hd][s]
  char* const Pw = (char*)&Ps[wv][0];
  const int qbase = qt * 64 + wv * 16;

  bf16x8 qa[2];
#pragma unroll
  for (int kk = 0; kk < 2; ++kk)
    qa[kk] = *(const bf16x8*)(Qp + (size_t)(qbase + (lane & 15)) * NHD
                              + kk * 32 + ((lane >> 4) << 3));

  f32x4 Of[4] = {};
  float mrow[4], lrow[4];
#pragma unroll
  for (int r = 0; r < 4; ++r) { mrow[r] = -1e30f; lrow[r] = 0.0f; }

  const int srow = (wv << 3) + (lane >> 3);
  const int scb  = (lane & 7) << 4;
  const int nkb = qt + 1;

#define STAGE_KV(buf, kbi_) do {                                               \
    _Pragma("unroll")                                                          \
    for (int i_ = 0; i_ < 2; ++i_) {                                           \
      const int row_ = i_ * 32 + srow;                                         \
      const int cb_ = scb ^ ((row_ & 7) << 4);                                 \
      gload16(Kp  + (size_t)((kbi_) * 64 + row_) * NHD + (cb_ >> 1),           \
              (char*)Ks[buf] + i_ * 4096 + wv * 1024);                         \
      gload16(Vtp + (size_t)row_ * NS + (kbi_) * 64 + (cb_ >> 1),              \
              (char*)Vts[buf] + i_ * 4096 + wv * 1024);                        \
    } } while (0)

  STAGE_KV(0, 0);
  __syncthreads();

  for (int kbi = 0; kbi < nkb; ++kbi) {
    const int cur = kbi & 1;
    if (kbi + 1 < nkb) STAGE_KV(cur ^ 1, kbi + 1);
    const bool maskedT = (kbi == qt);

    // ---- QK^T (scores already x log2e via Q pre-scale) ----
    f32x4 sf[4] = {};
    __builtin_amdgcn_s_setprio(1);
#pragma unroll
    for (int kk = 0; kk < 2; ++kk) {
#pragma unroll
      for (int f = 0; f < 4; ++f) {
        const int row = f * 16 + (lane & 15);
        const int cb = (kk * 64 + ((lane >> 4) << 4)) ^ ((row & 7) << 4);
        const bf16x8 kf = *(const bf16x8*)((const char*)Ks[cur] + row * 128 + cb);
        sf[f] = __builtin_amdgcn_mfma_f32_16x16x32_bf16(qa[kk], kf, sf[f], 0, 0, 0);
      }
    }
    __builtin_amdgcn_s_setprio(0);

    // ---- softmax (base-2: exp2f -> bare v_exp_f32) ----
    float tmax[4];
#pragma unroll
    for (int r = 0; r < 4; ++r) tmax[r] = -1e30f;
#pragma unroll
    for (int f = 0; f < 4; ++f)
#pragma unroll
      for (int r = 0; r < 4; ++r) {
        float sv = sf[f][r];
        if (maskedT) {
          const int kcol = kbi * 64 + f * 16 + (lane & 15);
          const int qrow = qbase + ((lane >> 4) << 2) + r;
          sv = (kcol <= qrow) ? sv : -1e30f;
          sf[f][r] = sv;
        }
        tmax[r] = fmaxf(tmax[r], sv);
      }
#pragma unroll
    for (int off = 8; off; off >>= 1)
#pragma unroll
      for (int r = 0; r < 4; ++r)
        tmax[r] = fmaxf(tmax[r], __shfl_xor(tmax[r], off, 64));
#pragma unroll
    for (int r = 0; r < 4; ++r) {
      const float mnew = fmaxf(mrow[r], tmax[r]);
      const float alpha = exp2f(mrow[r] - mnew);
      mrow[r] = mnew;
      float ps = 0.0f;
#pragma unroll
      for (int f = 0; f < 4; ++f) {
        const float p = exp2f(sf[f][r] - mnew);
        sf[f][r] = p;
        ps += p;
      }
      lrow[r] = lrow[r] * alpha + ps;
#pragma unroll
      for (int hf = 0; hf < 4; ++hf) Of[hf][r] *= alpha;
    }

    // ---- P store ----
#pragma unroll
    for (int f = 0; f < 4; ++f) {
      const int col = f * 16 + (lane & 15);
#pragma unroll
      for (int r = 0; r < 4; ++r) {
        const int prow = ((lane >> 4) << 2) + r;
        *(bf16*)(Pw + prow * 128 + ((col * 2) ^ ((prow & 7) << 4))) = (bf16)sf[f][r];
      }
    }

    // ---- PV ----
    __builtin_amdgcn_s_setprio(1);
#pragma unroll
    for (int kk = 0; kk < 2; ++kk) {
      const int prow = lane & 15;
      const int pcb = (kk * 64 + ((lane >> 4) << 4)) ^ ((prow & 7) << 4);
      const bf16x8 pa = *(const bf16x8*)(Pw + prow * 128 + pcb);
#pragma unroll
      for (int hf = 0; hf < 4; ++hf) {
        const int vrow = hf * 16 + (lane & 15);
        const int vcb = (kk * 64 + ((lane >> 4) << 4)) ^ ((vrow & 7) << 4);
        const bf16x8 vbf = *(const bf16x8*)((const char*)Vts[cur] + vrow * 128 + vcb);
        Of[hf] = __builtin_amdgcn_mfma_f32_16x16x32_bf16(pa, vbf, Of[hf], 0, 0, 0);
      }
    }
    __builtin_amdgcn_s_setprio(0);
    __syncthreads();
  }
#undef STAGE_KV

#pragma unroll
  for (int off = 8; off; off >>= 1)
#pragma unroll
    for (int r = 0; r < 4; ++r)
      lrow[r] += __shfl_xor(lrow[r], off, 64);
  const int b = bh >> 4, h = bh & 15;
#pragma unroll
  for (int r = 0; r < 4; ++r) {
    const float inv = 1.0f / lrow[r];
    const int q = qbase + ((lane >> 4) << 2) + r;
    bf16* dst = og + ((size_t)b * NS + q) * ND + h * NHD;
#pragma unroll
    for (int hf = 0; hf < 4; ++hf)
      dst[hf * 16 + (lane & 15)] = (bf16)(Of[hf][r] * inv);
  }
}

extern "C" void kernel_launch(void* const* d_in, const int* in_sizes, int n_in,
                              void* d_out, int out_size, void* d_ws, size_t ws_size,
                              hipStream_t stream) {
  (void)in_sizes; (void)n_in; (void)out_size; (void)ws_size;
  const float* x   = (const float*)d_in[0];
  const float* Wq  = (const float*)d_in[1];
  const float* bq  = (const float*)d_in[2];
  const float* Wk  = (const float*)d_in[3];
  const float* bk  = (const float*)d_in[4];
  const float* Wv  = (const float*)d_in[5];
  const float* bv  = (const float*)d_in[6];
  const float* Wp  = (const float*)d_in[7];
  const float* bp  = (const float*)d_in[8];
  const float* g1  = (const float*)d_in[9];
  const float* be1 = (const float*)d_in[10];
  const float* g2  = (const float*)d_in[11];
  const float* be2 = (const float*)d_in[12];
  const float* W1  = (const float*)d_in[13];
  const float* bf1 = (const float*)d_in[14];
  const float* W2  = (const float*)d_in[15];
  const float* bf2 = (const float*)d_in[16];
  float* outp = (float*)d_out;

  char* w = (char*)d_ws;
  bf16* WqT  = (bf16*)(w + (0u  << 20));
  bf16* WkT  = (bf16*)(w + (2u  << 20));
  bf16* WvT  = (bf16*)(w + (4u  << 20));
  bf16* WpT  = (bf16*)(w + (6u  << 20));
  bf16* W1T  = (bf16*)(w + (8u  << 20));
  bf16* W2T  = (bf16*)(w + (16u << 20));
  bf16* Abuf = (bf16*)(w + (24u << 20));
  bf16* qb   = (bf16*)(w + (32u << 20));
  bf16* kb   = (bf16*)(w + (40u << 20));
  bf16* vt   = (bf16*)(w + (48u << 20));  // V^T written directly by QKV epilogue
  bf16* ao   = (bf16*)(w + (56u << 20));
  bf16* hb   = (bf16*)(w + (32u << 20));  // reuses q/k/vt/ao region after proj
  float* x2  = outp;

  // fused: 6 weight transposes (3072 blocks) + LN1 (4096 blocks)
  tb_pre<<<7168, 256, 0, stream>>>(x, g1, be1, Abuf, Wq, Wk, Wv, Wp, W1, W2,
                                   WqT, WkT, WvT, WpT, W1T, W2T);
  // QKV projections; q pre-scaled 0.125*log2e; V written transposed to vt
  tb_gemm<0><<<dim3(8, 32, 3), 256, 0, stream>>>(Abuf, WqT, WkT, WvT, bq, bk, bv,
                                                 qb, kb, vt, ND);
  // causal attention -> ao [token][D]
  tb_attn<<<1024, 256, 0, stream>>>(qb, kb, vt, ao);
  // out proj + residual -> x2 (fp32, in d_out); 64x64 tiles, 4 blocks/CU
  tb_gemm64<<<1024, 256, 0, stream>>>(ao, WpT, bp, x, x2, ND);
  tb_lnorm<<<NM, 256, 0, stream>>>(x2, g2, be2, Abuf);
  // FFN1 + exact GELU -> h (bf16)
  tb_gemm<2><<<dim3(32, 32, 1), 256, 0, stream>>>(Abuf, W1T, W1T, W1T, bf1, bf1, bf1,
                                                  hb, hb, hb, ND);
  // FFN2 + residual -> d_out (fp32); 64x64 tiles, 4 blocks/CU
  tb_gemm64<<<1024, 256, 0, stream>>>(hb, W2T, bf2, x2, outp, NF);
}

// Round 20
// 227.789 us; speedup vs baseline: 1.0346x; 1.0346x over previous
//
#include <hip/hip_runtime.h>
#include <hip/hip_bf16.h>

#define AS1 __attribute__((address_space(1)))
#define AS3 __attribute__((address_space(3)))

typedef __bf16 bf16;
typedef __attribute__((ext_vector_type(8))) __bf16 bf16x8;
typedef __attribute__((ext_vector_type(4))) __bf16 bf16x4;
typedef __attribute__((ext_vector_type(4))) float f32x4;

#define NB 2
#define NS 2048
#define ND 1024
#define NH 16
#define NF 4096
#define NHD 64
#define NM (NB*NS)   // 4096 tokens

__device__ __forceinline__ void gload16(const void* g, void* l) {
  __builtin_amdgcn_global_load_lds((AS1 void*)g, (AS3 void*)l, 16, 0, 0);
}

// raw 2^x: v_exp_f32 + embedded s_nop 1 to cover the CDNA VALU-trans use
// hazard (compiler's hazard recognizer can't see inside inline asm; round 19
// without the s_nop produced timing-dependent corruption on graph replays).
__device__ __forceinline__ float fexp2(float x) {
  float r;
  asm("v_exp_f32 %0, %1\n\ts_nop 1" : "=v"(r) : "v"(x));
  return r;
}

// ---------------- fused prologue: 6 weight transposes (fp32->bf16) + LN1
// bid < 3072: weight transpose tiles.  bid >= 3072: LN1 row (bid-3072).
__global__ void tb_pre(const float* __restrict__ x, const float* __restrict__ g1,
                       const float* __restrict__ be1, bf16* __restrict__ Abuf,
                       const float* __restrict__ Wq, const float* __restrict__ Wk,
                       const float* __restrict__ Wv, const float* __restrict__ Wp,
                       const float* __restrict__ W1, const float* __restrict__ W2,
                       bf16* __restrict__ WqT, bf16* __restrict__ WkT,
                       bf16* __restrict__ WvT, bf16* __restrict__ WpT,
                       bf16* __restrict__ W1T, bf16* __restrict__ W2T) {
  __shared__ float t[64][65];
  __shared__ float red[8];
  const int bid = blockIdx.x;
  const int tid = threadIdx.x;
  if (bid >= 3072) {
    // ---- LN1 on row (bid-3072) ----
    const int row = bid - 3072;
    const float4 v = ((const float4*)(x + (size_t)row * ND))[tid];
    float s  = v.x + v.y + v.z + v.w;
    float ss = v.x*v.x + v.y*v.y + v.z*v.z + v.w*v.w;
#pragma unroll
    for (int off = 32; off; off >>= 1) {
      s  += __shfl_xor(s,  off, 64);
      ss += __shfl_xor(ss, off, 64);
    }
    const int lane = tid & 63, wv = tid >> 6;
    if (lane == 0) { red[wv] = s; red[4 + wv] = ss; }
    __syncthreads();
    s  = red[0] + red[1] + red[2] + red[3];
    ss = red[4] + red[5] + red[6] + red[7];
    const float mu = s * (1.0f / ND);
    const float var = ss * (1.0f / ND) - mu * mu;
    const float rstd = rsqrtf(var + 1e-5f);
    const float4 gv = ((const float4*)g1)[tid];
    const float4 bv = ((const float4*)be1)[tid];
    bf16x4 o;
    o[0] = (bf16)((v.x - mu) * rstd * gv.x + bv.x);
    o[1] = (bf16)((v.y - mu) * rstd * gv.y + bv.y);
    o[2] = (bf16)((v.z - mu) * rstd * gv.z + bv.z);
    o[3] = (bf16)((v.w - mu) * rstd * gv.w + bv.w);
    ((bf16x4*)(Abuf + (size_t)row * ND))[tid] = o;
    return;
  }
  // ---- weight transpose tile ----
  const float* W; bf16* Wt; int K, N, nb, kb;
  if (bid < 1024) {
    const int z = bid >> 8, i = bid & 255;
    K = ND; N = ND; nb = (i & 15) << 6; kb = (i >> 4) << 6;
    W  = (z == 0) ? Wq  : (z == 1) ? Wk  : (z == 2) ? Wv  : Wp;
    Wt = (z == 0) ? WqT : (z == 1) ? WkT : (z == 2) ? WvT : WpT;
  } else if (bid < 2048) {
    const int i = bid - 1024;
    K = ND; N = NF; nb = (i & 63) << 6; kb = (i >> 6) << 6;
    W = W1; Wt = W1T;
  } else {
    const int i = bid - 2048;
    K = NF; N = ND; nb = (i & 15) << 6; kb = (i >> 4) << 6;
    W = W2; Wt = W2T;
  }
#pragma unroll
  for (int i = 0; i < 16; ++i) {
    const int lin = tid + (i << 8);
    const int r = lin >> 6, c = lin & 63;
    t[r][c] = W[(size_t)(kb + r) * N + nb + c];
  }
  __syncthreads();
#pragma unroll
  for (int i = 0; i < 16; ++i) {
    const int lin = tid + (i << 8);
    const int r = lin >> 6, c = lin & 63;  // r: n-local, c: k-local
    Wt[(size_t)(nb + r) * K + kb + c] = (bf16)t[c][r];
  }
}

// ---------------- layernorm (LN2): fp32 row -> bf16 row (one block per row)
__global__ void tb_lnorm(const float* __restrict__ xin, const float* __restrict__ g,
                         const float* __restrict__ be, bf16* __restrict__ outp) {
  const int row = blockIdx.x;
  const int tid = threadIdx.x;
  const float4 v = ((const float4*)(xin + (size_t)row * ND))[tid];
  float s  = v.x + v.y + v.z + v.w;
  float ss = v.x*v.x + v.y*v.y + v.z*v.z + v.w*v.w;
#pragma unroll
  for (int off = 32; off; off >>= 1) {
    s  += __shfl_xor(s,  off, 64);
    ss += __shfl_xor(ss, off, 64);
  }
  __shared__ float red[8];
  const int lane = tid & 63, wv = tid >> 6;
  if (lane == 0) { red[wv] = s; red[4 + wv] = ss; }
  __syncthreads();
  s  = red[0] + red[1] + red[2] + red[3];
  ss = red[4] + red[5] + red[6] + red[7];
  const float mu = s * (1.0f / ND);
  const float var = ss * (1.0f / ND) - mu * mu;
  const float rstd = rsqrtf(var + 1e-5f);
  const float4 gv = ((const float4*)g)[tid];
  const float4 bv = ((const float4*)be)[tid];
  bf16x4 o;
  o[0] = (bf16)((v.x - mu) * rstd * gv.x + bv.x);
  o[1] = (bf16)((v.y - mu) * rstd * gv.y + bv.y);
  o[2] = (bf16)((v.z - mu) * rstd * gv.z + bv.z);
  o[3] = (bf16)((v.w - mu) * rstd * gv.w + bv.w);
  ((bf16x4*)(outp + (size_t)row * ND))[tid] = o;
}

// ---------------- GEMM 128x128: C = A * Bt^T (+bias epilogue)
// MODE 0: z==0 (Q, pre-scaled 0.125*log2e -> scores natively base-2) /
//         z==1 (K): bf16 scatter to [B,H,S,HD];
//         z==2 (V): write V^T directly to vt[bh][hd][s] via LDS transpose.
// MODE 2: out bf16 = gelu(acc + bias)     (stride NF)
template <int MODE>
__global__ void __launch_bounds__(256, 2)
tb_gemm(const bf16* __restrict__ A,
        const bf16* __restrict__ B0, const bf16* __restrict__ B1, const bf16* __restrict__ B2,
        const float* __restrict__ bias0, const float* __restrict__ bias1, const float* __restrict__ bias2,
        void* __restrict__ o0, void* __restrict__ o1, void* __restrict__ o2,
        int Ktot) {
  __shared__ __align__(16) bf16 SM[2][128 * 64];   // As = SM[0], Bs = SM[1]
  bf16* const As = SM[0];
  bf16* const Bs = SM[1];
  const bf16* Bt = B0; const float* bias = bias0; void* outp = o0;
  if (MODE == 0) {
    if (blockIdx.z == 1)      { Bt = B1; bias = bias1; outp = o1; }
    else if (blockIdx.z == 2) { Bt = B2; bias = bias2; outp = o2; }
  }
  const int tid = threadIdx.x;
  const int lane = tid & 63, wv = tid >> 6;
  const int wr = wv >> 1, wc = wv & 1;
  const int m0 = blockIdx.y * 128, n0 = blockIdx.x * 128;

  f32x4 acc[4][4] = {};

  const int srow = (wv << 3) + (lane >> 3);
  const int scb  = ((lane & 7) << 4);

  for (int k0 = 0; k0 < Ktot; k0 += 64) {
    __syncthreads();
#pragma unroll
    for (int i = 0; i < 4; ++i) {
      const int row = i * 32 + srow;
      const int cb = scb ^ ((row & 7) << 4);
      gload16(A  + (size_t)(m0 + row) * Ktot + k0 + (cb >> 1), (char*)As + i * 4096 + wv * 1024);
      gload16(Bt + (size_t)(n0 + row) * Ktot + k0 + (cb >> 1), (char*)Bs + i * 4096 + wv * 1024);
    }
    __syncthreads();
#pragma unroll
    for (int kk = 0; kk < 2; ++kk) {
      bf16x8 af[4], bfr[4];
#pragma unroll
      for (int mi = 0; mi < 4; ++mi) {
        const int row = wr * 64 + mi * 16 + (lane & 15);
        const int cb = (kk * 64 + ((lane >> 4) << 4)) ^ ((row & 7) << 4);
        af[mi] = *(const bf16x8*)((const char*)As + row * 128 + cb);
      }
#pragma unroll
      for (int ni = 0; ni < 4; ++ni) {
        const int row = wc * 64 + ni * 16 + (lane & 15);
        const int cb = (kk * 64 + ((lane >> 4) << 4)) ^ ((row & 7) << 4);
        bfr[ni] = *(const bf16x8*)((const char*)Bs + row * 128 + cb);
      }
#pragma unroll
      for (int mi = 0; mi < 4; ++mi)
#pragma unroll
        for (int ni = 0; ni < 4; ++ni)
          acc[mi][ni] = __builtin_amdgcn_mfma_f32_16x16x32_bf16(af[mi], bfr[ni], acc[mi][ni], 0, 0, 0);
    }
  }

  if (MODE == 0 && blockIdx.z == 2) {
    // ---- V: transpose via LDS, write vt[bh][hd][s] coalesced ----
    __syncthreads();                       // staging reads done; reuse SM
    bf16* const T = (bf16*)SM;             // [128 col][128 row], row^((col&7)<<3)
#pragma unroll
    for (int mi = 0; mi < 4; ++mi)
#pragma unroll
      for (int ni = 0; ni < 4; ++ni) {
        const int lcol = wc * 64 + ni * 16 + (lane & 15);
        const int lr0  = wr * 64 + mi * 16 + ((lane >> 4) << 2);
        bf16x4 tv;
#pragma unroll
        for (int r = 0; r < 4; ++r)
          tv[r] = (bf16)(acc[mi][ni][r] + bias[n0 + lcol]);
        *(bf16x4*)&T[lcol * 128 + (lr0 ^ ((lcol & 7) << 3))] = tv;
      }
    __syncthreads();
    const int col = tid & 127, rh = tid >> 7;
    const int gc = n0 + col, h = gc >> 6, hd = gc & 63;
    const int b = m0 >> 11, s0 = m0 & 2047;
    bf16* dst = (bf16*)outp + (((size_t)(b * NH + h)) * NHD + hd) * NS + s0 + rh * 64;
#pragma unroll
    for (int bb = 0; bb < 8; ++bb) {
      const int blk = rh * 8 + bb;
      *(bf16x8*)(dst + bb * 8) =
          *(const bf16x8*)&T[col * 128 + ((blk << 3) ^ ((col & 7) << 3))];
    }
    return;
  }

  // Q pre-scale folds 1/sqrt(HD) AND log2(e): scores become base-2 exponents.
  const float scale = (MODE == 0 && blockIdx.z == 0) ? 0.18033688f : 1.0f;
#pragma unroll
  for (int mi = 0; mi < 4; ++mi) {
#pragma unroll
    for (int ni = 0; ni < 4; ++ni) {
      const int rbase = m0 + wr * 64 + mi * 16 + ((lane >> 4) << 2);
      const int gcol  = n0 + wc * 64 + ni * 16 + (lane & 15);
#pragma unroll
      for (int r = 0; r < 4; ++r) {
        const int grow = rbase + r;
        const float val = (acc[mi][ni][r] + bias[gcol]) * scale;
        if (MODE == 0) {
          const int b = grow >> 11, sIdx = grow & 2047;
          const int h = gcol >> 6, hd = gcol & 63;
          ((bf16*)outp)[(((size_t)(b * NH + h)) * NS + sIdx) * NHD + hd] = (bf16)val;
        } else {
          const float gelu = 0.5f * val * (1.0f + erff(val * 0.70710678f));
          ((bf16*)outp)[(size_t)grow * NF + gcol] = (bf16)gelu;
        }
      }
    }
  }
}

// ---------------- GEMM 64x64 + residual (proj & FFN2): occupancy-first tile
// Grid 1024 blocks (64 m x 16 n), 32KB LDS -> 4 blocks/CU.
// XCD m-grouped: each XCD owns 8 m-panels (4MB A, L2-resident); B L3-served.
__global__ void __launch_bounds__(256, 4)
tb_gemm64(const bf16* __restrict__ A, const bf16* __restrict__ Bt,
          const float* __restrict__ bias, const float* __restrict__ resid,
          float* __restrict__ outp, int Ktot) {
  __shared__ __align__(16) bf16 As[2][64 * 64];
  __shared__ __align__(16) bf16 Bs[2][64 * 64];
  const int bid = blockIdx.x;            // 0..1023
  const int xcd = bid & 7, j = bid >> 3; // j: 0..127
  const int m0 = (xcd * 8 + (j & 7)) * 64;   // 64 m-tiles, 8 per XCD
  const int n0 = (j >> 3) * 64;              // 16 n-tiles
  const int tid = threadIdx.x;
  const int lane = tid & 63, wv = tid >> 6;
  const int wr = wv >> 1, wc = wv & 1;       // wave tile: 32 x 32

  f32x4 acc[2][2] = {};

  const int srow = (wv << 3) + (lane >> 3);
  const int scb  = ((lane & 7) << 4);
  const int NT = Ktot >> 6;

#define GSTAGE64(buf, t_) do {                                                 \
    _Pragma("unroll")                                                          \
    for (int i_ = 0; i_ < 2; ++i_) {                                           \
      const int row_ = i_ * 32 + srow;                                         \
      const int cb_ = scb ^ ((row_ & 7) << 4);                                 \
      gload16(A  + (size_t)(m0 + row_) * Ktot + ((t_) << 6) + (cb_ >> 1),      \
              (char*)As[buf] + i_ * 4096 + wv * 1024);                         \
      gload16(Bt + (size_t)(n0 + row_) * Ktot + ((t_) << 6) + (cb_ >> 1),      \
              (char*)Bs[buf] + i_ * 4096 + wv * 1024);                         \
    } } while (0)

  GSTAGE64(0, 0);
  asm volatile("s_waitcnt vmcnt(0)" ::: "memory");
  __builtin_amdgcn_s_barrier();

  for (int t = 0; t < NT; ++t) {
    const int cur = t & 1;
    if (t + 1 < NT) GSTAGE64(cur ^ 1, t + 1);   // prefetch flies under MFMA
    const char* Ab = (const char*)As[cur];
    const char* Bb = (const char*)Bs[cur];
#pragma unroll
    for (int kk = 0; kk < 2; ++kk) {
      bf16x8 af[2], bfr[2];
#pragma unroll
      for (int mi = 0; mi < 2; ++mi) {
        const int row = wr * 32 + mi * 16 + (lane & 15);
        const int cb = (kk * 64 + ((lane >> 4) << 4)) ^ ((row & 7) << 4);
        af[mi] = *(const bf16x8*)(Ab + row * 128 + cb);
      }
#pragma unroll
      for (int ni = 0; ni < 2; ++ni) {
        const int row = wc * 32 + ni * 16 + (lane & 15);
        const int cb = (kk * 64 + ((lane >> 4) << 4)) ^ ((row & 7) << 4);
        bfr[ni] = *(const bf16x8*)(Bb + row * 128 + cb);
      }
#pragma unroll
      for (int mi = 0; mi < 2; ++mi)
#pragma unroll
        for (int ni = 0; ni < 2; ++ni)
          acc[mi][ni] = __builtin_amdgcn_mfma_f32_16x16x32_bf16(af[mi], bfr[ni], acc[mi][ni], 0, 0, 0);
    }
    if (t + 1 < NT) {
      asm volatile("s_waitcnt vmcnt(0)" ::: "memory");
      __builtin_amdgcn_s_barrier();
    }
  }
#undef GSTAGE64

  // epilogue: out = resid + acc + bias (fp32, stride ND)
#pragma unroll
  for (int mi = 0; mi < 2; ++mi) {
#pragma unroll
    for (int ni = 0; ni < 2; ++ni) {
      const int rbase = m0 + wr * 32 + mi * 16 + ((lane >> 4) << 2);
      const int gcol  = n0 + wc * 32 + ni * 16 + (lane & 15);
#pragma unroll
      for (int r = 0; r < 4; ++r) {
        const size_t idx = (size_t)(rbase + r) * ND + gcol;
        outp[idx] = resid[idx] + acc[mi][ni][r] + bias[gcol];
      }
    }
  }
}

// ---------------- causal flash attention (base-2 scores, hazard-safe exp; T5)
__global__ void __launch_bounds__(256, 4)
tb_attn(const bf16* __restrict__ qg, const bf16* __restrict__ kg,
        const bf16* __restrict__ vtg, bf16* __restrict__ og) {
  __shared__ __align__(16) bf16 Ks[2][64 * 64];
  __shared__ __align__(16) bf16 Vts[2][64 * 64];
  __shared__ __align__(16) bf16 Ps[4][16 * 64];
  const int bid = blockIdx.x;
  const int u = bid & 255, v = bid >> 8;
  const int bh = u & 31;
  const int s = ((u >> 5) << 2) + v;                    // 0..31
  const int qt = (s & 1) ? (31 - (s >> 1)) : (s >> 1);  // balanced per-CU mix
  const int tid = threadIdx.x;
  const int lane = tid & 63, wv = tid >> 6;
  const bf16* Qp  = qg  + (size_t)bh * NS * NHD;
  const bf16* Kp  = kg  + (size_t)bh * NS * NHD;
  const bf16* Vtp = vtg + (size_t)bh * NHD * NS;   // [hd][s]
  char* const Pw = (char*)&Ps[wv][0];
  const int qbase = qt * 64 + wv * 16;

  bf16x8 qa[2];
#pragma unroll
  for (int kk = 0; kk < 2; ++kk)
    qa[kk] = *(const bf16x8*)(Qp + (size_t)(qbase + (lane & 15)) * NHD
                              + kk * 32 + ((lane >> 4) << 3));

  f32x4 Of[4] = {};
  float mrow[4], lrow[4];
#pragma unroll
  for (int r = 0; r < 4; ++r) { mrow[r] = -1e30f; lrow[r] = 0.0f; }

  const int srow = (wv << 3) + (lane >> 3);
  const int scb  = (lane & 7) << 4;
  const int nkb = qt + 1;

#define STAGE_KV(buf, kbi_) do {                                               \
    _Pragma("unroll")                                                          \
    for (int i_ = 0; i_ < 2; ++i_) {                                           \
      const int row_ = i_ * 32 + srow;                                         \
      const int cb_ = scb ^ ((row_ & 7) << 4);                                 \
      gload16(Kp  + (size_t)((kbi_) * 64 + row_) * NHD + (cb_ >> 1),           \
              (char*)Ks[buf] + i_ * 4096 + wv * 1024);                         \
      gload16(Vtp + (size_t)row_ * NS + (kbi_) * 64 + (cb_ >> 1),              \
              (char*)Vts[buf] + i_ * 4096 + wv * 1024);                        \
    } } while (0)

  STAGE_KV(0, 0);
  __syncthreads();

  for (int kbi = 0; kbi < nkb; ++kbi) {
    const int cur = kbi & 1;
    if (kbi + 1 < nkb) STAGE_KV(cur ^ 1, kbi + 1);
    const bool maskedT = (kbi == qt);

    // ---- QK^T (scores already x log2e via Q pre-scale) ----
    f32x4 sf[4] = {};
    __builtin_amdgcn_s_setprio(1);
#pragma unroll
    for (int kk = 0; kk < 2; ++kk) {
#pragma unroll
      for (int f = 0; f < 4; ++f) {
        const int row = f * 16 + (lane & 15);
        const int cb = (kk * 64 + ((lane >> 4) << 4)) ^ ((row & 7) << 4);
        const bf16x8 kf = *(const bf16x8*)((const char*)Ks[cur] + row * 128 + cb);
        sf[f] = __builtin_amdgcn_mfma_f32_16x16x32_bf16(qa[kk], kf, sf[f], 0, 0, 0);
      }
    }
    __builtin_amdgcn_s_setprio(0);

    // ---- softmax (base-2: hazard-safe v_exp_f32) ----
    float tmax[4];
#pragma unroll
    for (int r = 0; r < 4; ++r) tmax[r] = -1e30f;
#pragma unroll
    for (int f = 0; f < 4; ++f)
#pragma unroll
      for (int r = 0; r < 4; ++r) {
        float sv = sf[f][r];
        if (maskedT) {
          const int kcol = kbi * 64 + f * 16 + (lane & 15);
          const int qrow = qbase + ((lane >> 4) << 2) + r;
          sv = (kcol <= qrow) ? sv : -1e30f;
          sf[f][r] = sv;
        }
        tmax[r] = fmaxf(tmax[r], sv);
      }
#pragma unroll
    for (int off = 8; off; off >>= 1)
#pragma unroll
      for (int r = 0; r < 4; ++r)
        tmax[r] = fmaxf(tmax[r], __shfl_xor(tmax[r], off, 64));
#pragma unroll
    for (int r = 0; r < 4; ++r) {
      const float mnew = fmaxf(mrow[r], tmax[r]);
      const float alpha = fexp2(mrow[r] - mnew);
      mrow[r] = mnew;
      float ps = 0.0f;
#pragma unroll
      for (int f = 0; f < 4; ++f) {
        const float p = fexp2(sf[f][r] - mnew);
        sf[f][r] = p;
        ps += p;
      }
      lrow[r] = lrow[r] * alpha + ps;
#pragma unroll
      for (int hf = 0; hf < 4; ++hf) Of[hf][r] *= alpha;
    }

    // ---- P store ----
#pragma unroll
    for (int f = 0; f < 4; ++f) {
      const int col = f * 16 + (lane & 15);
#pragma unroll
      for (int r = 0; r < 4; ++r) {
        const int prow = ((lane >> 4) << 2) + r;
        *(bf16*)(Pw + prow * 128 + ((col * 2) ^ ((prow & 7) << 4))) = (bf16)sf[f][r];
      }
    }

    // ---- PV ----
    __builtin_amdgcn_s_setprio(1);
#pragma unroll
    for (int kk = 0; kk < 2; ++kk) {
      const int prow = lane & 15;
      const int pcb = (kk * 64 + ((lane >> 4) << 4)) ^ ((prow & 7) << 4);
      const bf16x8 pa = *(const bf16x8*)(Pw + prow * 128 + pcb);
#pragma unroll
      for (int hf = 0; hf < 4; ++hf) {
        const int vrow = hf * 16 + (lane & 15);
        const int vcb = (kk * 64 + ((lane >> 4) << 4)) ^ ((vrow & 7) << 4);
        const bf16x8 vbf = *(const bf16x8*)((const char*)Vts[cur] + vrow * 128 + vcb);
        Of[hf] = __builtin_amdgcn_mfma_f32_16x16x32_bf16(pa, vbf, Of[hf], 0, 0, 0);
      }
    }
    __builtin_amdgcn_s_setprio(0);
    __syncthreads();
  }
#undef STAGE_KV

#pragma unroll
  for (int off = 8; off; off >>= 1)
#pragma unroll
    for (int r = 0; r < 4; ++r)
      lrow[r] += __shfl_xor(lrow[r], off, 64);
  const int b = bh >> 4, h = bh & 15;
#pragma unroll
  for (int r = 0; r < 4; ++r) {
    const float inv = 1.0f / lrow[r];
    const int q = qbase + ((lane >> 4) << 2) + r;
    bf16* dst = og + ((size_t)b * NS + q) * ND + h * NHD;
#pragma unroll
    for (int hf = 0; hf < 4; ++hf)
      dst[hf * 16 + (lane & 15)] = (bf16)(Of[hf][r] * inv);
  }
}

extern "C" void kernel_launch(void* const* d_in, const int* in_sizes, int n_in,
                              void* d_out, int out_size, void* d_ws, size_t ws_size,
                              hipStream_t stream) {
  (void)in_sizes; (void)n_in; (void)out_size; (void)ws_size;
  const float* x   = (const float*)d_in[0];
  const float* Wq  = (const float*)d_in[1];
  const float* bq  = (const float*)d_in[2];
  const float* Wk  = (const float*)d_in[3];
  const float* bk  = (const float*)d_in[4];
  const float* Wv  = (const float*)d_in[5];
  const float* bv  = (const float*)d_in[6];
  const float* Wp  = (const float*)d_in[7];
  const float* bp  = (const float*)d_in[8];
  const float* g1  = (const float*)d_in[9];
  const float* be1 = (const float*)d_in[10];
  const float* g2  = (const float*)d_in[11];
  const float* be2 = (const float*)d_in[12];
  const float* W1  = (const float*)d_in[13];
  const float* bf1 = (const float*)d_in[14];
  const float* W2  = (const float*)d_in[15];
  const float* bf2 = (const float*)d_in[16];
  float* outp = (float*)d_out;

  char* w = (char*)d_ws;
  bf16* WqT  = (bf16*)(w + (0u  << 20));
  bf16* WkT  = (bf16*)(w + (2u  << 20));
  bf16* WvT  = (bf16*)(w + (4u  << 20));
  bf16* WpT  = (bf16*)(w + (6u  << 20));
  bf16* W1T  = (bf16*)(w + (8u  << 20));
  bf16* W2T  = (bf16*)(w + (16u << 20));
  bf16* Abuf = (bf16*)(w + (24u << 20));
  bf16* qb   = (bf16*)(w + (32u << 20));
  bf16* kb   = (bf16*)(w + (40u << 20));
  bf16* vt   = (bf16*)(w + (48u << 20));  // V^T written directly by QKV epilogue
  bf16* ao   = (bf16*)(w + (56u << 20));
  bf16* hb   = (bf16*)(w + (32u << 20));  // reuses q/k/vt/ao region after proj
  float* x2  = outp;

  // fused: 6 weight transposes (3072 blocks) + LN1 (4096 blocks)
  tb_pre<<<7168, 256, 0, stream>>>(x, g1, be1, Abuf, Wq, Wk, Wv, Wp, W1, W2,
                                   WqT, WkT, WvT, WpT, W1T, W2T);
  // QKV projections; q pre-scaled 0.125*log2e; V written transposed to vt
  tb_gemm<0><<<dim3(8, 32, 3), 256, 0, stream>>>(Abuf, WqT, WkT, WvT, bq, bk, bv,
                                                 qb, kb, vt, ND);
  // causal attention -> ao [token][D]
  tb_attn<<<1024, 256, 0, stream>>>(qb, kb, vt, ao);
  // out proj + residual -> x2 (fp32, in d_out); 64x64 tiles, 4 blocks/CU
  tb_gemm64<<<1024, 256, 0, stream>>>(ao, WpT, bp, x, x2, ND);
  tb_lnorm<<<NM, 256, 0, stream>>>(x2, g2, be2, Abuf);
  // FFN1 + exact GELU -> h (bf16)
  tb_gemm<2><<<dim3(32, 32, 1), 256, 0, stream>>>(Abuf, W1T, W1T, W1T, bf1, bf1, bf1,
                                                  hb, hb, hb, ND);
  // FFN2 + residual -> d_out (fp32); 64x64 tiles, 4 blocks/CU
  tb_gemm64<<<1024, 256, 0, stream>>>(hb, W2T, bf2, x2, outp, NF);
}